// Round 10
// baseline (1153.591 us; speedup 1.0000x reference)
//
#include <hip/hip_runtime.h>
#include <math.h>

// Problem constants
constexpr int NN = 1024;   // nodes
constexpr int DD = 256;    // input dim
constexpr int HH = 64;     // hidden
constexpr int CC = 20;     // chains
constexpr int EE = 16384;  // edges

// workspace layout (float offsets)
constexpr size_t WS_NE1  = 0;
constexpr size_t WS_NE   = WS_NE1  + (size_t)NN*HH;
constexpr size_t WS_S    = WS_NE   + (size_t)NN*HH;      // states [C][N][H]
constexpr size_t WS_NP   = WS_S    + (size_t)CC*NN*HH;   // nodes_part [C][N][H]
constexpr size_t WS_MASK = WS_NP   + (size_t)CC*NN*HH;   // [N]
constexpr size_t WS_AG1  = WS_MASK + NN;                 // [N][H]
constexpr size_t WS_PART = WS_AG1  + (size_t)NN*HH;      // split-K partials, 8*[N][H]

#define DEV __device__ __forceinline__

DEV void fma4(float4& a, float s, const float4& b) {
  a.x = fmaf(s, b.x, a.x); a.y = fmaf(s, b.y, a.y);
  a.z = fmaf(s, b.z, a.z); a.w = fmaf(s, b.w, a.w);
}
DEV void add4(float4& a, const float4& b) { a.x += b.x; a.y += b.y; a.z += b.z; a.w += b.w; }
DEV float dot4(const float4& a, const float4& b) {
  return fmaf(a.x, b.x, fmaf(a.y, b.y, fmaf(a.z, b.z, a.w * b.w)));
}
DEV float sigm(float x) { return 1.f / (1.f + __expf(-x)); }
// score accumulate: s += sum_h relu(p_h + v_h) * w_h  (4 h at a time; 3 VALU ops/h = floor)
DEV void score_acc(float& s, const float4& p, const float4& v, const float4& w) {
  s = fmaf(fmaxf(p.x + v.x, 0.f), w.x, s);
  s = fmaf(fmaxf(p.y + v.y, 0.f), w.y, s);
  s = fmaf(fmaxf(p.z + v.z, 0.f), w.z, s);
  s = fmaf(fmaxf(p.w + v.w, 0.f), w.w, s);
}

// stage a 64x64 fp32 tile (row-major) into LDS with XOR f4-column swizzle:
// logical [row][q] stored at d4[row*16 + (q ^ ((row>>1)&15))] -> stride-64 col reads 2-way max
DEV void stage64(float* dst, const float* __restrict__ src, int tid) {
  const float4* s4 = (const float4*)src;
  float4* d4 = (float4*)dst;
  #pragma unroll
  for (int r = 0; r < 4; ++r) {
    int idx = tid + r * 256;
    int row = idx >> 4, q = idx & 15;
    d4[row * 16 + (q ^ ((row >> 1) & 15))] = s4[idx];
  }
}

// ---------------- generic 64-row x 64-col tile GEMM (unchanged, verified)
template <int MODE>
__global__ __launch_bounds__(256) void gemm_k(
    const float* __restrict__ A, const float* __restrict__ B,
    const float* __restrict__ bias, float* __restrict__ Out,
    int lda, int K, int ldb, int ksplit, long bBatch, long oBatch) {
  __shared__ float At[16][68];
  __shared__ float Bt[16][64];
  const int tid = threadIdx.x;
  const int m0 = blockIdx.x * 64;
  const int n0 = blockIdx.y * 64;
  const int kbase = blockIdx.z * ksplit;
  const float* Bp = B + (long)blockIdx.z * bBatch;
  const int rg = tid >> 4, jg = tid & 15;
  float4 acc[4];
  #pragma unroll
  for (int i = 0; i < 4; ++i) acc[i] = make_float4(0, 0, 0, 0);
  const int rA = tid >> 2, kqA = tid & 3;
  const int kkB = tid >> 4, qB = tid & 15;
  for (int kk = 0; kk < K; kk += 16) {
    const int k0 = kbase + kk;
    float4 av = *(const float4*)(A + (size_t)(m0 + rA) * lda + k0 + kqA * 4);
    At[kqA * 4 + 0][rA] = av.x;
    At[kqA * 4 + 1][rA] = av.y;
    At[kqA * 4 + 2][rA] = av.z;
    At[kqA * 4 + 3][rA] = av.w;
    *(float4*)&Bt[kkB][qB * 4] = *(const float4*)(Bp + (size_t)(k0 + kkB) * ldb + n0 + qB * 4);
    __syncthreads();
    #pragma unroll
    for (int k = 0; k < 16; ++k) {
      float4 a4 = *(const float4*)&At[k][rg * 4];
      float4 b4 = *(const float4*)&Bt[k][jg * 4];
      fma4(acc[0], a4.x, b4); fma4(acc[1], a4.y, b4);
      fma4(acc[2], a4.z, b4); fma4(acc[3], a4.w, b4);
    }
    __syncthreads();
  }
  float4 bv = make_float4(0, 0, 0, 0);
  if (bias) bv = *(const float4*)(bias + n0 + jg * 4);
  #pragma unroll
  for (int i = 0; i < 4; ++i) {
    int rr = m0 + rg * 4 + i;
    float4 v = acc[i];
    add4(v, bv);
    if (MODE == 1) {
      v.x = fmaxf(v.x, 0.f); v.y = fmaxf(v.y, 0.f);
      v.z = fmaxf(v.z, 0.f); v.w = fmaxf(v.w, 0.f);
    }
    if (MODE == 2) {
      *(float4*)(Out + ((size_t)blockIdx.y * NN + rr) * HH + jg * 4) = v;
    } else {
      *(float4*)(Out + (long)blockIdx.z * oBatch + (size_t)rr * HH + jg * 4) = v;
    }
  }
}

template <int Z, int RELU>
__global__ __launch_bounds__(256) void reduceZ_k(
    const float* __restrict__ part, const float* __restrict__ bias, float* __restrict__ dst) {
  int i = blockIdx.x * 256 + threadIdx.x;
  float4 v = ((const float4*)part)[i];
  #pragma unroll
  for (int z = 1; z < Z; ++z) add4(v, ((const float4*)part)[z * 16384 + i]);
  float4 bv = ((const float4*)bias)[i & 15];
  add4(v, bv);
  if (RELU) {
    v.x = fmaxf(v.x, 0.f); v.y = fmaxf(v.y, 0.f);
    v.z = fmaxf(v.z, 0.f); v.w = fmaxf(v.w, 0.f);
  }
  ((float4*)dst)[i] = v;
}

__global__ __launch_bounds__(256) void zero_mask_k(float* m) {
  int i = blockIdx.x * 256 + threadIdx.x;
  if (i < NN) m[i] = 0.f;
}
__global__ __launch_bounds__(256) void scatter_mask_k(const int* __restrict__ e, float* m) {
  int i = blockIdx.x * 256 + threadIdx.x;
  if (i < EE) m[e[2 * i + 1]] = 1.0f;
}

// ---------------- fused attention + GRU step (block = one chain x 32 rows)
// History: r5 split kernel (old softmax + 6-chunk GRU): 286us/step @ VGPR=108, 3 blk/CU.
// r9 merged 3-step kernel (no-max softmax + 3-pass GRU): 1063us total @ VGPR=220 —
// merge blew the register budget (allocator keeps union of all phases + bases live)
// -> 2 blk/CU, REGRESSION. r10: back to SPLIT dispatches (measured-good occupancy)
// keeping the algorithmic wins: no-max softmax (scores stat-bounded |s|<~5; softmax
// shift-invariant; one lane-reduce/step) and 3-pass 2-col GRU (ctx/s read 3x not 6x).
__global__ __launch_bounds__(256) void fused_step(
    const float* __restrict__ ne_g, const float* __restrict__ np_g,
    const float* __restrict__ mask_g,
    const float* __restrict__ Wa1, const float* __restrict__ ba1,
    const float* __restrict__ Wa2, const float* __restrict__ ba2,
    const float* __restrict__ Wih, const float* __restrict__ Whh,
    const float* __restrict__ bih, const float* __restrict__ bhh,
    float* __restrict__ s_g, float* __restrict__ stk) {
  __shared__ __align__(16) float bufN[64 * 64];  // w_state / np tile / Wih chunk
  __shared__ __align__(16) float bufE[64 * 64];  // ne tile / Whh chunk
  __shared__ __align__(16) float preD[32 * 64];  // pre -> ctx
  __shared__ __align__(16) float pbuf[32 * 64];  // s rows <-> p_t
  __shared__ __align__(16) float wa2_t[64];
  __shared__ float mask_t[64];
  __shared__ float l_run[32];

  const int tid = threadIdx.x;
  const int c = blockIdx.y;
  const int b0 = blockIdx.x * 32;

  // ---- stage s rows into pbuf, w_state into bufN, wa2 ----
  {
    const float4* sg4 = (const float4*)(s_g + ((size_t)c * NN + b0) * HH);
    ((float4*)pbuf)[tid] = sg4[tid];
    ((float4*)pbuf)[tid + 256] = sg4[tid + 256];
  }
  stage64(bufN, Wa1 + (size_t)c * 8192, tid);  // w_state = Wa1[c][0:64]
  if (tid < 16) ((float4*)wa2_t)[tid] = ((const float4*)(Wa2 + c * 64))[tid];
  __syncthreads();

  // pre[b][h] = s[b] @ w_state + ba1[c]
  {
    const int bb = tid >> 4, hb = tid & 15;
    float4 a0 = make_float4(0, 0, 0, 0), a1 = a0;
    const float4* st4 = (const float4*)pbuf;
    const float4* w4p = (const float4*)bufN;
    #pragma unroll
    for (int kq = 0; kq < 16; ++kq) {
      float4 s0 = st4[(bb * 2 + 0) * 16 + kq];
      float4 s1 = st4[(bb * 2 + 1) * 16 + kq];
      float4 w0 = w4p[(kq * 4 + 0) * 16 + (hb ^ (((kq * 4 + 0) >> 1) & 15))];
      float4 w1 = w4p[(kq * 4 + 1) * 16 + (hb ^ (((kq * 4 + 1) >> 1) & 15))];
      float4 w2 = w4p[(kq * 4 + 2) * 16 + (hb ^ (((kq * 4 + 2) >> 1) & 15))];
      float4 w3 = w4p[(kq * 4 + 3) * 16 + (hb ^ (((kq * 4 + 3) >> 1) & 15))];
      fma4(a0, s0.x, w0); fma4(a0, s0.y, w1); fma4(a0, s0.z, w2); fma4(a0, s0.w, w3);
      fma4(a1, s1.x, w0); fma4(a1, s1.y, w1); fma4(a1, s1.z, w2); fma4(a1, s1.w, w3);
    }
    float4 bia = ((const float4*)(ba1 + c * 64))[hb];
    add4(a0, bia); add4(a1, bia);
    ((float4*)preD)[(bb * 2 + 0) * 16 + hb] = a0;
    ((float4*)preD)[(bb * 2 + 1) * 16 + hb] = a1;
  }
  // stash s to registers; pbuf becomes p_t
  float4 sstash0 = ((const float4*)pbuf)[tid * 2];
  float4 sstash1 = ((const float4*)pbuf)[tid * 2 + 1];
  __syncthreads();

  const float ba2c = ba2[c];
  const int sbg = tid >> 5;   // score/GRU: b-group (4 rows each)
  const int sng = tid & 31;   // score: n-group (2 cols) / GRU: j col
  const int slc = tid >> 6;   // ctx: wave-slice 0..3
  const int cu  = tid & 63;
  const int cb4 = cu & 7;     // ctx: b-group
  const int chd = cu >> 3;    // ctx: h-pair (f4-quads 2*chd, 2*chd+1)

  float4 cacc[4][2];
  #pragma unroll
  for (int i = 0; i < 4; ++i) {
    cacc[i][0] = make_float4(0, 0, 0, 0);
    cacc[i][1] = make_float4(0, 0, 0, 0);
  }
  float lpart[4] = {0, 0, 0, 0};

  // ---- n loop: 16 tiles of 64 (unroll-pinned: reg pressure) ----
  #pragma unroll 1
  for (int t = 0; t < 16; ++t) {
    const int n0t = t * 64;
    stage64(bufN, np_g + ((size_t)c * NN + n0t) * HH, tid);
    stage64(bufE, ne_g + (size_t)n0t * HH, tid);
    if (tid < 64) mask_t[tid] = mask_g[n0t + tid];
    __syncthreads();

    // scores: 4b x 2n per thread
    float sc[4][2] = {{0, 0}, {0, 0}, {0, 0}, {0, 0}};
    {
      const float4* pre4 = (const float4*)preD;
      const float4* np4 = (const float4*)bufN;
      const int nA = sng * 2, nB = sng * 2 + 1;
      const int fA = (nA >> 1) & 15;
      #pragma unroll
      for (int hc = 0; hc < 16; ++hc) {
        float4 w4 = ((const float4*)wa2_t)[hc];
        float4 p0 = pre4[(sbg * 4 + 0) * 16 + hc];
        float4 p1 = pre4[(sbg * 4 + 1) * 16 + hc];
        float4 p2 = pre4[(sbg * 4 + 2) * 16 + hc];
        float4 p3 = pre4[(sbg * 4 + 3) * 16 + hc];
        float4 v0 = np4[nA * 16 + (hc ^ fA)];
        float4 v1 = np4[nB * 16 + (hc ^ fA)];
        score_acc(sc[0][0], p0, v0, w4); score_acc(sc[0][1], p0, v1, w4);
        score_acc(sc[1][0], p1, v0, w4); score_acc(sc[1][1], p1, v1, w4);
        score_acc(sc[2][0], p2, v0, w4); score_acc(sc[2][1], p2, v1, w4);
        score_acc(sc[3][0], p3, v0, w4); score_acc(sc[3][1], p3, v1, w4);
      }
    }
    // softmax-lite: no running max; p straight to pbuf, per-thread l partial
    {
      const int nA = sng * 2, nB = sng * 2 + 1;
      float mk0 = mask_t[nA], mk1 = mask_t[nB];
      float p[4][2];
      #pragma unroll
      for (int i = 0; i < 4; ++i) {
        p[i][0] = __expf((sc[i][0] + ba2c) * mk0);
        p[i][1] = __expf((sc[i][1] + ba2c) * mk1);
        lpart[i] += p[i][0] + p[i][1];
      }
      // p_t[n][b] with b-offset XOR-swizzled by (n>>1)&7: writes 4-way, reads conflict-free
      const int swz = (sng & 7) * 4;
      *(float4*)&pbuf[nA * 32 + ((sbg * 4) ^ swz)] = make_float4(p[0][0], p[1][0], p[2][0], p[3][0]);
      *(float4*)&pbuf[nB * 32 + ((sbg * 4) ^ swz)] = make_float4(p[0][1], p[1][1], p[2][1], p[3][1]);
    }
    __syncthreads();

    // ctx accumulate (pure, no rescale): wave slc handles n = slc*16..+15
    {
      const float4* ne4 = (const float4*)bufE;
      #pragma unroll 4
      for (int k = 0; k < 16; ++k) {
        int n = slc * 16 + k;
        float4 pv = *(const float4*)&pbuf[n * 32 + ((cb4 * 4) ^ (((n >> 1) & 7) * 4))];
        int f = (n >> 1) & 15;
        float4 e0 = ne4[n * 16 + ((chd * 2 + 0) ^ f)];
        float4 e1 = ne4[n * 16 + ((chd * 2 + 1) ^ f)];
        fma4(cacc[0][0], pv.x, e0); fma4(cacc[0][1], pv.x, e1);
        fma4(cacc[1][0], pv.y, e0); fma4(cacc[1][1], pv.y, e1);
        fma4(cacc[2][0], pv.z, e0); fma4(cacc[2][1], pv.z, e1);
        fma4(cacc[3][0], pv.w, e0); fma4(cacc[3][1], pv.w, e1);
      }
    }
    __syncthreads();
  }

  // ---- one lane-reduce of l (replaces per-tile shuffle reduces) ----
  #pragma unroll
  for (int o = 16; o > 0; o >>= 1) {
    #pragma unroll
    for (int i = 0; i < 4; ++i) lpart[i] += __shfl_xor(lpart[i], o, 32);
  }
  if (sng == 0) {
    #pragma unroll
    for (int i = 0; i < 4; ++i) l_run[sbg * 4 + i] = lpart[i];
  }
  // restore s rows (p_t dead; published by merge barriers below)
  ((float4*)pbuf)[tid * 2] = sstash0;
  ((float4*)pbuf)[tid * 2 + 1] = sstash1;

  // ---- merge 4 wave-slices of ctx into preD; normalize by l ----
  {
    float* ctx_l = preD;
    if (slc == 0) {
      #pragma unroll
      for (int i = 0; i < 4; ++i) {
        *(float4*)&ctx_l[(cb4 * 4 + i) * 64 + (chd * 2 + 0) * 4] = cacc[i][0];
        *(float4*)&ctx_l[(cb4 * 4 + i) * 64 + (chd * 2 + 1) * 4] = cacc[i][1];
      }
    }
    __syncthreads();
    #pragma unroll 1
    for (int s2 = 1; s2 < 4; ++s2) {
      if (slc == s2) {
        #pragma unroll
        for (int i = 0; i < 4; ++i) {
          float4* d0 = (float4*)&ctx_l[(cb4 * 4 + i) * 64 + (chd * 2 + 0) * 4];
          float4* d1 = (float4*)&ctx_l[(cb4 * 4 + i) * 64 + (chd * 2 + 1) * 4];
          float4 t0 = *d0, t1 = *d1;
          add4(t0, cacc[i][0]); add4(t1, cacc[i][1]);
          *d0 = t0; *d1 = t1;
        }
      }
      __syncthreads();
    }
    for (int e = tid; e < 2048; e += 256) ctx_l[e] = ctx_l[e] / l_run[e >> 6];
  }

  // ---- GRU: 3 passes (r, z, cand), 2 output cols/thread; ctx/s read 3x not 6x ----
  {
    float rr0[4], rr1[4], zz0[4], zz1[4];
    const int jg = sng, bg = sbg;
    const int fj = (jg >> 1) & 15;  // note ((jg+32)>>1)&15 == fj
    #pragma unroll 1
    for (int pass = 0; pass < 3; ++pass) {
      __syncthreads();  // orders normalize writes (pass 0) / prev-pass reads before restage
      stage64(bufN, Wih + ((size_t)c * 192 + pass * 64) * 64, tid);
      stage64(bufE, Whh + ((size_t)c * 192 + pass * 64) * 64, tid);
      __syncthreads();
      float gi0[4] = {0, 0, 0, 0}, gi1[4] = {0, 0, 0, 0};
      float gh0[4] = {0, 0, 0, 0}, gh1[4] = {0, 0, 0, 0};
      const float4* cx4 = (const float4*)preD;
      const float4* st4 = (const float4*)pbuf;
      const float4* wi4 = (const float4*)bufN;
      const float4* wh4 = (const float4*)bufE;
      #pragma unroll
      for (int kq = 0; kq < 16; ++kq) {
        float4 wi0 = wi4[jg * 16 + (kq ^ fj)];
        float4 wi1 = wi4[(jg + 32) * 16 + (kq ^ fj)];
        float4 wh0 = wh4[jg * 16 + (kq ^ fj)];
        float4 wh1 = wh4[(jg + 32) * 16 + (kq ^ fj)];
        #pragma unroll
        for (int i = 0; i < 4; ++i) {
          float4 cx = cx4[(bg * 4 + i) * 16 + kq];
          float4 sx = st4[(bg * 4 + i) * 16 + kq];
          gi0[i] += dot4(cx, wi0); gi1[i] += dot4(cx, wi1);
          gh0[i] += dot4(sx, wh0); gh1[i] += dot4(sx, wh1);
        }
      }
      const int j0 = pass * 64 + jg, j1 = j0 + 32;
      const float bi0 = bih[c * 192 + j0], bh0 = bhh[c * 192 + j0];
      const float bi1 = bih[c * 192 + j1], bh1 = bhh[c * 192 + j1];
      if (pass == 0) {
        #pragma unroll
        for (int i = 0; i < 4; ++i) {
          rr0[i] = sigm(gi0[i] + bi0 + gh0[i] + bh0);
          rr1[i] = sigm(gi1[i] + bi1 + gh1[i] + bh1);
        }
      } else if (pass == 1) {
        #pragma unroll
        for (int i = 0; i < 4; ++i) {
          zz0[i] = sigm(gi0[i] + bi0 + gh0[i] + bh0);
          zz1[i] = sigm(gi1[i] + bi1 + gh1[i] + bh1);
        }
      } else {
        // final pass: write s_g (and stk on last step) directly — no pbuf update needed
        #pragma unroll
        for (int i = 0; i < 4; ++i) {
          int b = bg * 4 + i;
          float cand0 = tanhf(gi0[i] + bi0 + rr0[i] * (gh0[i] + bh0));
          float cand1 = tanhf(gi1[i] + bi1 + rr1[i] * (gh1[i] + bh1));
          float ns0 = (1.f - zz0[i]) * cand0 + zz0[i] * pbuf[b * 64 + jg];
          float ns1 = (1.f - zz1[i]) * cand1 + zz1[i] * pbuf[b * 64 + jg + 32];
          s_g[((size_t)c * NN + b0 + b) * HH + jg] = ns0;
          s_g[((size_t)c * NN + b0 + b) * HH + jg + 32] = ns1;
          if (stk) {
            stk[((size_t)(b0 + b)) * (CC * HH) + c * HH + jg] = ns0;
            stk[((size_t)(b0 + b)) * (CC * HH) + c * HH + jg + 32] = ns1;
          }
        }
      }
    }
  }
}

// ---------------- fused epilogue: Wag2 GEMM + chain-attn + pred (unchanged)
__global__ __launch_bounds__(256) void attn_pred_k(
    const float* __restrict__ ag1, const float* __restrict__ s,
    const float* __restrict__ Wag2, const float* __restrict__ bag2,
    const float* __restrict__ Wp, const float* __restrict__ bp,
    float* __restrict__ fin_g, float* __restrict__ attn, float* __restrict__ pred) {
  __shared__ __align__(16) float W2t[64 * 68];
  __shared__ float agL[4 * 64];
  __shared__ float wpL[64];
  const int tid = threadIdx.x;
  const int n0 = blockIdx.x * 4;
  #pragma unroll
  for (int t = 0; t < 4; ++t) {
    int idx = tid + t * 256;
    int r = idx >> 4, q = idx & 15;
    *(float4*)&W2t[r * 68 + q * 4] = ((const float4*)Wag2)[idx];
  }
  if (tid < 4 * 64) agL[tid] = ag1[(size_t)n0 * 64 + tid];
  if (tid < 64) wpL[tid] = Wp[tid];
  __syncthreads();

  const int w = tid >> 6, l = tid & 63;
  const int n = n0 + w;
  float fin = bag2[l];
  #pragma unroll
  for (int k = 0; k < 64; ++k) fin = fmaf(agL[w * 64 + k], W2t[k * 68 + l], fin);
  fin_g[(size_t)n * 64 + l] = fin;

  float sc[CC];
  #pragma unroll
  for (int c2 = 0; c2 < CC; ++c2) {
    float v = fin * s[((size_t)c2 * NN + n) * 64 + l];
    #pragma unroll
    for (int o = 32; o > 0; o >>= 1) v += __shfl_xor(v, o, 64);
    sc[c2] = v;
  }
  float m = sc[0];
  #pragma unroll
  for (int c2 = 1; c2 < CC; ++c2) m = fmaxf(m, sc[c2]);
  float sum = 0.f;
  float p[CC];
  #pragma unroll
  for (int c2 = 0; c2 < CC; ++c2) { p[c2] = __expf(sc[c2] - m); sum += p[c2]; }
  float inv = 1.f / sum;
  if (l == 0) {
    #pragma unroll
    for (int c2 = 0; c2 < CC; ++c2) attn[n * CC + c2] = p[c2] * inv;
  }
  float pv = fin * wpL[l];
  #pragma unroll
  for (int o = 32; o > 0; o >>= 1) pv += __shfl_xor(pv, o, 64);
  if (l == 0) pred[n] = pv + bp[0];
}

extern "C" void kernel_launch(void* const* d_in, const int* in_sizes, int n_in,
                              void* d_out, int out_size, void* d_ws, size_t ws_size,
                              hipStream_t stream) {
  (void)in_sizes; (void)n_in; (void)out_size; (void)ws_size;
  const float* nf   = (const float*)d_in[0];
  const int*   edg  = (const int*)d_in[1];
  const float* Wt1  = (const float*)d_in[2];
  const float* bt1  = (const float*)d_in[3];
  const float* Wt2  = (const float*)d_in[4];
  const float* bt2  = (const float*)d_in[5];
  const float* Wci  = (const float*)d_in[6];
  const float* bci  = (const float*)d_in[7];
  const float* Wa1  = (const float*)d_in[8];
  const float* ba1  = (const float*)d_in[9];
  const float* Wa2  = (const float*)d_in[10];
  const float* ba2  = (const float*)d_in[11];
  const float* Wih  = (const float*)d_in[12];
  const float* Whh  = (const float*)d_in[13];
  const float* bih  = (const float*)d_in[14];
  const float* bhh  = (const float*)d_in[15];
  const float* Wag1 = (const float*)d_in[16];
  const float* bag1 = (const float*)d_in[17];
  const float* Wag2 = (const float*)d_in[18];
  const float* bag2 = (const float*)d_in[19];
  const float* Wp   = (const float*)d_in[20];
  const float* bp   = (const float*)d_in[21];

  float* ws   = (float*)d_ws;
  float* ne1  = ws + WS_NE1;
  float* ne   = ws + WS_NE;
  float* s    = ws + WS_S;
  float* np   = ws + WS_NP;
  float* mask = ws + WS_MASK;
  float* ag1  = ws + WS_AG1;
  float* part = ws + WS_PART;

  float* out_stacked = (float*)d_out;                       // [N][C][H]
  float* out_final   = out_stacked + (size_t)NN * CC * HH;  // [N][H]
  float* out_attn    = out_final + (size_t)NN * HH;         // [N][C]
  float* out_pred    = out_attn + (size_t)NN * CC;          // [N]

  // mask (independent)
  zero_mask_k<<<4, 256, 0, stream>>>(mask);
  scatter_mask_k<<<EE / 256, 256, 0, stream>>>(edg, mask);
  // trunk layer 1: split-K=4 over K=256
  gemm_k<0><<<dim3(16, 1, 4), 256, 0, stream>>>(nf, Wt1, nullptr, part, DD, 64, HH, 64, 0, (long)NN * HH);
  reduceZ_k<4, 1><<<64, 256, 0, stream>>>(part, bt1, ne1);
  // trunk layer 2
  gemm_k<1><<<dim3(16, 1, 1), 256, 0, stream>>>(ne1, Wt2, bt2, ne, HH, HH, HH, 0, 0, 0);
  // states0 -> s[c][n][h]
  gemm_k<2><<<dim3(16, CC, 1), 256, 0, stream>>>(ne, Wci, bci, s, HH, HH, CC * HH, 0, 0, 0);
  // nodes_part[c] = ne @ Wa1[c][64:128]
  gemm_k<0><<<dim3(16, 1, CC), 256, 0, stream>>>(ne, Wa1 + HH * HH, nullptr, np, HH, HH, HH, 0,
                                                 (long)2 * HH * HH, (long)NN * HH);
  // 3 sequential fused steps (split dispatches = measured-good occupancy);
  // step 2 also writes out_stacked (fused transpose)
  for (int step = 0; step < 3; ++step)
    fused_step<<<dim3(32, CC), 256, 0, stream>>>(ne, np, mask, Wa1, ba1, Wa2, ba2,
                                                 Wih, Whh, bih, bhh, s,
                                                 step == 2 ? out_stacked : nullptr);
  // aggregate layer 1: split-K=8 over K=1280
  gemm_k<0><<<dim3(16, 1, 8), 256, 0, stream>>>(out_stacked, Wag1, nullptr, part, CC * HH, 160, HH,
                                                160, 0, (long)NN * HH);
  reduceZ_k<8, 1><<<64, 256, 0, stream>>>(part, bag1, ag1);
  // fused: final = ag1 @ Wag2 + bag2; chain-attention softmax; pred
  attn_pred_k<<<NN / 4, 256, 0, stream>>>(ag1, s, Wag2, bag2, Wp, bp,
                                          out_final, out_attn, out_pred);
}

// Round 11
// 869.975 us; speedup vs baseline: 1.3260x; 1.3260x over previous
//
#include <hip/hip_runtime.h>
#include <math.h>

// Problem constants
constexpr int NN = 1024;   // nodes
constexpr int DD = 256;    // input dim
constexpr int HH = 64;     // hidden
constexpr int CC = 20;     // chains
constexpr int EE = 16384;  // edges

// workspace layout (float offsets)
constexpr size_t WS_NE1  = 0;
constexpr size_t WS_NE   = WS_NE1  + (size_t)NN*HH;
constexpr size_t WS_S    = WS_NE   + (size_t)NN*HH;      // states [C][N][H]
constexpr size_t WS_NP   = WS_S    + (size_t)CC*NN*HH;   // nodes_part [C][N][H]
constexpr size_t WS_MASK = WS_NP   + (size_t)CC*NN*HH;   // [N]
constexpr size_t WS_AG1  = WS_MASK + NN;                 // [N][H]
constexpr size_t WS_PART = WS_AG1  + (size_t)NN*HH;      // split-K partials, 8*[N][H]

#define DEV __device__ __forceinline__

DEV void fma4(float4& a, float s, const float4& b) {
  a.x = fmaf(s, b.x, a.x); a.y = fmaf(s, b.y, a.y);
  a.z = fmaf(s, b.z, a.z); a.w = fmaf(s, b.w, a.w);
}
DEV void add4(float4& a, const float4& b) { a.x += b.x; a.y += b.y; a.z += b.z; a.w += b.w; }
DEV float dot4(const float4& a, const float4& b) {
  return fmaf(a.x, b.x, fmaf(a.y, b.y, fmaf(a.z, b.z, a.w * b.w)));
}
DEV float sigm(float x) { return 1.f / (1.f + __expf(-x)); }
// score accumulate: s += sum_h relu(p_h + v_h) * w_h  (4 h at a time; 3 VALU ops/h = floor)
DEV void score_acc(float& s, const float4& p, const float4& v, const float4& w) {
  s = fmaf(fmaxf(p.x + v.x, 0.f), w.x, s);
  s = fmaf(fmaxf(p.y + v.y, 0.f), w.y, s);
  s = fmaf(fmaxf(p.z + v.z, 0.f), w.z, s);
  s = fmaf(fmaxf(p.w + v.w, 0.f), w.w, s);
}

// stage a 64x64 fp32 tile (row-major) into LDS with XOR f4-column swizzle:
// logical [row][q] stored at d4[row*16 + (q ^ ((row>>1)&15))] -> stride-64 col reads 2-way max
DEV void stage64(float* dst, const float* __restrict__ src, int tid) {
  const float4* s4 = (const float4*)src;
  float4* d4 = (float4*)dst;
  #pragma unroll
  for (int r = 0; r < 4; ++r) {
    int idx = tid + r * 256;
    int row = idx >> 4, q = idx & 15;
    d4[row * 16 + (q ^ ((row >> 1) & 15))] = s4[idx];
  }
}
// 32-row variant
DEV void stage32(float* dst, const float* __restrict__ src, int tid) {
  const float4* s4 = (const float4*)src;
  float4* d4 = (float4*)dst;
  #pragma unroll
  for (int r = 0; r < 2; ++r) {
    int idx = tid + r * 256;
    int row = idx >> 4, q = idx & 15;
    d4[row * 16 + (q ^ ((row >> 1) & 15))] = s4[idx];
  }
}

// ---------------- generic 64-row x 64-col tile GEMM (unchanged, verified)
template <int MODE>
__global__ __launch_bounds__(256) void gemm_k(
    const float* __restrict__ A, const float* __restrict__ B,
    const float* __restrict__ bias, float* __restrict__ Out,
    int lda, int K, int ldb, int ksplit, long bBatch, long oBatch) {
  __shared__ float At[16][68];
  __shared__ float Bt[16][64];
  const int tid = threadIdx.x;
  const int m0 = blockIdx.x * 64;
  const int n0 = blockIdx.y * 64;
  const int kbase = blockIdx.z * ksplit;
  const float* Bp = B + (long)blockIdx.z * bBatch;
  const int rg = tid >> 4, jg = tid & 15;
  float4 acc[4];
  #pragma unroll
  for (int i = 0; i < 4; ++i) acc[i] = make_float4(0, 0, 0, 0);
  const int rA = tid >> 2, kqA = tid & 3;
  const int kkB = tid >> 4, qB = tid & 15;
  for (int kk = 0; kk < K; kk += 16) {
    const int k0 = kbase + kk;
    float4 av = *(const float4*)(A + (size_t)(m0 + rA) * lda + k0 + kqA * 4);
    At[kqA * 4 + 0][rA] = av.x;
    At[kqA * 4 + 1][rA] = av.y;
    At[kqA * 4 + 2][rA] = av.z;
    At[kqA * 4 + 3][rA] = av.w;
    *(float4*)&Bt[kkB][qB * 4] = *(const float4*)(Bp + (size_t)(k0 + kkB) * ldb + n0 + qB * 4);
    __syncthreads();
    #pragma unroll
    for (int k = 0; k < 16; ++k) {
      float4 a4 = *(const float4*)&At[k][rg * 4];
      float4 b4 = *(const float4*)&Bt[k][jg * 4];
      fma4(acc[0], a4.x, b4); fma4(acc[1], a4.y, b4);
      fma4(acc[2], a4.z, b4); fma4(acc[3], a4.w, b4);
    }
    __syncthreads();
  }
  float4 bv = make_float4(0, 0, 0, 0);
  if (bias) bv = *(const float4*)(bias + n0 + jg * 4);
  #pragma unroll
  for (int i = 0; i < 4; ++i) {
    int rr = m0 + rg * 4 + i;
    float4 v = acc[i];
    add4(v, bv);
    if (MODE == 1) {
      v.x = fmaxf(v.x, 0.f); v.y = fmaxf(v.y, 0.f);
      v.z = fmaxf(v.z, 0.f); v.w = fmaxf(v.w, 0.f);
    }
    if (MODE == 2) {
      *(float4*)(Out + ((size_t)blockIdx.y * NN + rr) * HH + jg * 4) = v;
    } else {
      *(float4*)(Out + (long)blockIdx.z * oBatch + (size_t)rr * HH + jg * 4) = v;
    }
  }
}

template <int Z, int RELU>
__global__ __launch_bounds__(256) void reduceZ_k(
    const float* __restrict__ part, const float* __restrict__ bias, float* __restrict__ dst) {
  int i = blockIdx.x * 256 + threadIdx.x;
  float4 v = ((const float4*)part)[i];
  #pragma unroll
  for (int z = 1; z < Z; ++z) add4(v, ((const float4*)part)[z * 16384 + i]);
  float4 bv = ((const float4*)bias)[i & 15];
  add4(v, bv);
  if (RELU) {
    v.x = fmaxf(v.x, 0.f); v.y = fmaxf(v.y, 0.f);
    v.z = fmaxf(v.z, 0.f); v.w = fmaxf(v.w, 0.f);
  }
  ((float4*)dst)[i] = v;
}

__global__ __launch_bounds__(256) void zero_mask_k(float* m) {
  int i = blockIdx.x * 256 + threadIdx.x;
  if (i < NN) m[i] = 0.f;
}
__global__ __launch_bounds__(256) void scatter_mask_k(const int* __restrict__ e, float* m) {
  int i = blockIdx.x * 256 + threadIdx.x;
  if (i < EE) m[e[2 * i + 1]] = 1.0f;
}

// ---------------- fused attention + GRU step (block = one chain x 32 rows)
// Bisection history (per-step time @ VGPR @ blocks/CU):
//   r5:  old softmax + 6-chunk GRU : 286us @ 108 @ 3   <- baseline structure
//   r9:  merged 3 steps            : 354us @ 220 @ 2   <- merge blew regs, reverted
//   r10: no-max SM + 3-pass GRU    : 361us @ 176 @ 2   <- 3-pass 2-col GRU = +68 VGPR,
//        crossed the 128 boundary (waves/SIMD 3->2). Bank conflicts identical to r5
//        => score/ctx work unchanged; occupancy was the whole regression.
//   r11: no-max SM + 6-chunk GRU (this) — keep softmax's DS-op savings (zero reg cost,
//        lpart[4] only), revert GRU to the 1-col form measured at 108 VGPR.
__global__ __launch_bounds__(256) void fused_step(
    const float* __restrict__ ne_g, const float* __restrict__ np_g,
    const float* __restrict__ mask_g,
    const float* __restrict__ Wa1, const float* __restrict__ ba1,
    const float* __restrict__ Wa2, const float* __restrict__ ba2,
    const float* __restrict__ Wih, const float* __restrict__ Whh,
    const float* __restrict__ bih, const float* __restrict__ bhh,
    float* __restrict__ s_g, float* __restrict__ stk) {
  __shared__ __align__(16) float bufN[64 * 64];  // w_state / np tile / GRU weight chunks
  __shared__ __align__(16) float bufE[64 * 64];  // ne tile
  __shared__ __align__(16) float preD[32 * 64];  // pre -> ctx
  __shared__ __align__(16) float pbuf[32 * 64];  // s rows <-> p_t
  __shared__ __align__(16) float wa2_t[64];
  __shared__ float mask_t[64];
  __shared__ float l_run[32];

  const int tid = threadIdx.x;
  const int c = blockIdx.y;
  const int b0 = blockIdx.x * 32;

  // ---- stage s rows into pbuf, w_state into bufN, wa2 ----
  {
    const float4* sg4 = (const float4*)(s_g + ((size_t)c * NN + b0) * HH);
    ((float4*)pbuf)[tid] = sg4[tid];
    ((float4*)pbuf)[tid + 256] = sg4[tid + 256];
  }
  stage64(bufN, Wa1 + (size_t)c * 8192, tid);  // w_state = Wa1[c][0:64]
  if (tid < 16) ((float4*)wa2_t)[tid] = ((const float4*)(Wa2 + c * 64))[tid];
  __syncthreads();

  // pre[b][h] = s[b] @ w_state + ba1[c]
  {
    const int bb = tid >> 4, hb = tid & 15;
    float4 a0 = make_float4(0, 0, 0, 0), a1 = a0;
    const float4* st4 = (const float4*)pbuf;
    const float4* w4p = (const float4*)bufN;
    #pragma unroll
    for (int kq = 0; kq < 16; ++kq) {
      float4 s0 = st4[(bb * 2 + 0) * 16 + kq];
      float4 s1 = st4[(bb * 2 + 1) * 16 + kq];
      float4 w0 = w4p[(kq * 4 + 0) * 16 + (hb ^ (((kq * 4 + 0) >> 1) & 15))];
      float4 w1 = w4p[(kq * 4 + 1) * 16 + (hb ^ (((kq * 4 + 1) >> 1) & 15))];
      float4 w2 = w4p[(kq * 4 + 2) * 16 + (hb ^ (((kq * 4 + 2) >> 1) & 15))];
      float4 w3 = w4p[(kq * 4 + 3) * 16 + (hb ^ (((kq * 4 + 3) >> 1) & 15))];
      fma4(a0, s0.x, w0); fma4(a0, s0.y, w1); fma4(a0, s0.z, w2); fma4(a0, s0.w, w3);
      fma4(a1, s1.x, w0); fma4(a1, s1.y, w1); fma4(a1, s1.z, w2); fma4(a1, s1.w, w3);
    }
    float4 bia = ((const float4*)(ba1 + c * 64))[hb];
    add4(a0, bia); add4(a1, bia);
    ((float4*)preD)[(bb * 2 + 0) * 16 + hb] = a0;
    ((float4*)preD)[(bb * 2 + 1) * 16 + hb] = a1;
  }
  // stash s to registers; pbuf becomes p_t
  float4 sstash0 = ((const float4*)pbuf)[tid * 2];
  float4 sstash1 = ((const float4*)pbuf)[tid * 2 + 1];
  __syncthreads();

  const float ba2c = ba2[c];
  const int sbg = tid >> 5;   // score: b-group (4 rows each)
  const int sng = tid & 31;   // score: n-group (2 cols each)
  const int slc = tid >> 6;   // ctx: wave-slice 0..3
  const int cu  = tid & 63;
  const int cb4 = cu & 7;     // ctx: b-group
  const int chd = cu >> 3;    // ctx: h-pair (f4-quads 2*chd, 2*chd+1)

  float4 cacc[4][2];
  #pragma unroll
  for (int i = 0; i < 4; ++i) {
    cacc[i][0] = make_float4(0, 0, 0, 0);
    cacc[i][1] = make_float4(0, 0, 0, 0);
  }
  float lpart[4] = {0, 0, 0, 0};

  // ---- n loop: 16 tiles of 64 (unroll-pinned: reg pressure) ----
  #pragma unroll 1
  for (int t = 0; t < 16; ++t) {
    const int n0t = t * 64;
    stage64(bufN, np_g + ((size_t)c * NN + n0t) * HH, tid);
    stage64(bufE, ne_g + (size_t)n0t * HH, tid);
    if (tid < 64) mask_t[tid] = mask_g[n0t + tid];
    __syncthreads();

    // scores: 4b x 2n per thread
    float sc[4][2] = {{0, 0}, {0, 0}, {0, 0}, {0, 0}};
    {
      const float4* pre4 = (const float4*)preD;
      const float4* np4 = (const float4*)bufN;
      const int nA = sng * 2, nB = sng * 2 + 1;
      const int fA = (nA >> 1) & 15;
      #pragma unroll
      for (int hc = 0; hc < 16; ++hc) {
        float4 w4 = ((const float4*)wa2_t)[hc];
        float4 p0 = pre4[(sbg * 4 + 0) * 16 + hc];
        float4 p1 = pre4[(sbg * 4 + 1) * 16 + hc];
        float4 p2 = pre4[(sbg * 4 + 2) * 16 + hc];
        float4 p3 = pre4[(sbg * 4 + 3) * 16 + hc];
        float4 v0 = np4[nA * 16 + (hc ^ fA)];
        float4 v1 = np4[nB * 16 + (hc ^ fA)];
        score_acc(sc[0][0], p0, v0, w4); score_acc(sc[0][1], p0, v1, w4);
        score_acc(sc[1][0], p1, v0, w4); score_acc(sc[1][1], p1, v1, w4);
        score_acc(sc[2][0], p2, v0, w4); score_acc(sc[2][1], p2, v1, w4);
        score_acc(sc[3][0], p3, v0, w4); score_acc(sc[3][1], p3, v1, w4);
      }
    }
    // softmax-lite: no running max (scores stat-bounded |s|<~5; shift-invariant);
    // p straight to pbuf, per-thread l partial — zero extra persistent regs (lpart[4])
    {
      const int nA = sng * 2, nB = sng * 2 + 1;
      float mk0 = mask_t[nA], mk1 = mask_t[nB];
      float p[4][2];
      #pragma unroll
      for (int i = 0; i < 4; ++i) {
        p[i][0] = __expf((sc[i][0] + ba2c) * mk0);
        p[i][1] = __expf((sc[i][1] + ba2c) * mk1);
        lpart[i] += p[i][0] + p[i][1];
      }
      // p_t[n][b] with b-offset XOR-swizzled by (n>>1)&7: writes 4-way, reads conflict-free
      const int swz = (sng & 7) * 4;
      *(float4*)&pbuf[nA * 32 + ((sbg * 4) ^ swz)] = make_float4(p[0][0], p[1][0], p[2][0], p[3][0]);
      *(float4*)&pbuf[nB * 32 + ((sbg * 4) ^ swz)] = make_float4(p[0][1], p[1][1], p[2][1], p[3][1]);
    }
    __syncthreads();

    // ctx accumulate (pure, no rescale): wave slc handles n = slc*16..+15
    {
      const float4* ne4 = (const float4*)bufE;
      #pragma unroll 4
      for (int k = 0; k < 16; ++k) {
        int n = slc * 16 + k;
        float4 pv = *(const float4*)&pbuf[n * 32 + ((cb4 * 4) ^ (((n >> 1) & 7) * 4))];
        int f = (n >> 1) & 15;
        float4 e0 = ne4[n * 16 + ((chd * 2 + 0) ^ f)];
        float4 e1 = ne4[n * 16 + ((chd * 2 + 1) ^ f)];
        fma4(cacc[0][0], pv.x, e0); fma4(cacc[0][1], pv.x, e1);
        fma4(cacc[1][0], pv.y, e0); fma4(cacc[1][1], pv.y, e1);
        fma4(cacc[2][0], pv.z, e0); fma4(cacc[2][1], pv.z, e1);
        fma4(cacc[3][0], pv.w, e0); fma4(cacc[3][1], pv.w, e1);
      }
    }
    __syncthreads();
  }

  // ---- one lane-reduce of l (replaces per-tile shuffle reduces) ----
  #pragma unroll
  for (int o = 16; o > 0; o >>= 1) {
    #pragma unroll
    for (int i = 0; i < 4; ++i) lpart[i] += __shfl_xor(lpart[i], o, 32);
  }
  if (sng == 0) {
    #pragma unroll
    for (int i = 0; i < 4; ++i) l_run[sbg * 4 + i] = lpart[i];
  }
  // restore s rows (p_t dead; published by merge barriers below)
  ((float4*)pbuf)[tid * 2] = sstash0;
  ((float4*)pbuf)[tid * 2 + 1] = sstash1;

  // ---- merge 4 wave-slices of ctx into preD; normalize by l ----
  {
    float* ctx_l = preD;
    if (slc == 0) {
      #pragma unroll
      for (int i = 0; i < 4; ++i) {
        *(float4*)&ctx_l[(cb4 * 4 + i) * 64 + (chd * 2 + 0) * 4] = cacc[i][0];
        *(float4*)&ctx_l[(cb4 * 4 + i) * 64 + (chd * 2 + 1) * 4] = cacc[i][1];
      }
    }
    __syncthreads();
    #pragma unroll 1
    for (int s2 = 1; s2 < 4; ++s2) {
      if (slc == s2) {
        #pragma unroll
        for (int i = 0; i < 4; ++i) {
          float4* d0 = (float4*)&ctx_l[(cb4 * 4 + i) * 64 + (chd * 2 + 0) * 4];
          float4* d1 = (float4*)&ctx_l[(cb4 * 4 + i) * 64 + (chd * 2 + 1) * 4];
          float4 t0 = *d0, t1 = *d1;
          add4(t0, cacc[i][0]); add4(t1, cacc[i][1]);
          *d0 = t0; *d1 = t1;
        }
      }
      __syncthreads();
    }
    for (int e = tid; e < 2048; e += 256) ctx_l[e] = ctx_l[e] / l_run[e >> 6];
  }

  // ---- GRU: 6 chunks of 32 output cols, 1 col/thread (r5 form, 108-VGPR measured);
  //      r,z kept in registers (same thread produces/consumes) ----
  {
    float r0[4], r1[4], z0[4], z1[4];
    const int jg = tid & 31, bg = tid >> 5;
    const int fj = (jg >> 1) & 15;
    #pragma unroll 1
    for (int ch = 0; ch < 6; ++ch) {
      __syncthreads();  // orders normalize writes (ch 0) / prev-chunk reads before restage
      stage32(bufN,        Wih + ((size_t)c * 192 + ch * 32) * 64, tid);
      stage32(bufN + 2048, Whh + ((size_t)c * 192 + ch * 32) * 64, tid);
      __syncthreads();
      float gi[4] = {0, 0, 0, 0}, gh[4] = {0, 0, 0, 0};
      const float4* cx4 = (const float4*)preD;
      const float4* st4 = (const float4*)pbuf;
      const float4* wi4 = (const float4*)bufN;
      const float4* wh4 = (const float4*)(bufN + 2048);
      #pragma unroll
      for (int kq = 0; kq < 16; ++kq) {
        float4 wi = wi4[jg * 16 + (kq ^ fj)];
        float4 wh = wh4[jg * 16 + (kq ^ fj)];
        #pragma unroll
        for (int i = 0; i < 4; ++i) {
          float4 cx = cx4[(bg * 4 + i) * 16 + kq];
          float4 sx = st4[(bg * 4 + i) * 16 + kq];
          gi[i] += dot4(cx, wi);
          gh[i] += dot4(sx, wh);
        }
      }
      const int jglob = ch * 32 + jg;
      const float bi = bih[c * 192 + jglob];
      const float bh = bhh[c * 192 + jglob];
      if (ch == 0) {
        #pragma unroll
        for (int i = 0; i < 4; ++i) r0[i] = sigm(gi[i] + bi + gh[i] + bh);
      } else if (ch == 1) {
        #pragma unroll
        for (int i = 0; i < 4; ++i) r1[i] = sigm(gi[i] + bi + gh[i] + bh);
      } else if (ch == 2) {
        #pragma unroll
        for (int i = 0; i < 4; ++i) z0[i] = sigm(gi[i] + bi + gh[i] + bh);
      } else if (ch == 3) {
        #pragma unroll
        for (int i = 0; i < 4; ++i) z1[i] = sigm(gi[i] + bi + gh[i] + bh);
      } else {
        #pragma unroll
        for (int i = 0; i < 4; ++i) {
          int b = bg * 4 + i;
          int jl = (ch - 4) * 32 + jg;
          float r = (ch == 4) ? r0[i] : r1[i];
          float z = (ch == 4) ? z0[i] : z1[i];
          float cand = tanhf(gi[i] + bi + r * (gh[i] + bh));
          float sv = pbuf[b * 64 + jl];
          float nsv = (1.f - z) * cand + z * sv;
          s_g[((size_t)c * NN + b0 + b) * HH + jl] = nsv;
          if (stk) stk[((size_t)(b0 + b)) * (CC * HH) + c * HH + jl] = nsv;  // fused transpose
        }
      }
    }
  }
}

// ---------------- fused epilogue: Wag2 GEMM + chain-attn + pred (unchanged)
__global__ __launch_bounds__(256) void attn_pred_k(
    const float* __restrict__ ag1, const float* __restrict__ s,
    const float* __restrict__ Wag2, const float* __restrict__ bag2,
    const float* __restrict__ Wp, const float* __restrict__ bp,
    float* __restrict__ fin_g, float* __restrict__ attn, float* __restrict__ pred) {
  __shared__ __align__(16) float W2t[64 * 68];
  __shared__ float agL[4 * 64];
  __shared__ float wpL[64];
  const int tid = threadIdx.x;
  const int n0 = blockIdx.x * 4;
  #pragma unroll
  for (int t = 0; t < 4; ++t) {
    int idx = tid + t * 256;
    int r = idx >> 4, q = idx & 15;
    *(float4*)&W2t[r * 68 + q * 4] = ((const float4*)Wag2)[idx];
  }
  if (tid < 4 * 64) agL[tid] = ag1[(size_t)n0 * 64 + tid];
  if (tid < 64) wpL[tid] = Wp[tid];
  __syncthreads();

  const int w = tid >> 6, l = tid & 63;
  const int n = n0 + w;
  float fin = bag2[l];
  #pragma unroll
  for (int k = 0; k < 64; ++k) fin = fmaf(agL[w * 64 + k], W2t[k * 68 + l], fin);
  fin_g[(size_t)n * 64 + l] = fin;

  float sc[CC];
  #pragma unroll
  for (int c2 = 0; c2 < CC; ++c2) {
    float v = fin * s[((size_t)c2 * NN + n) * 64 + l];
    #pragma unroll
    for (int o = 32; o > 0; o >>= 1) v += __shfl_xor(v, o, 64);
    sc[c2] = v;
  }
  float m = sc[0];
  #pragma unroll
  for (int c2 = 1; c2 < CC; ++c2) m = fmaxf(m, sc[c2]);
  float sum = 0.f;
  float p[CC];
  #pragma unroll
  for (int c2 = 0; c2 < CC; ++c2) { p[c2] = __expf(sc[c2] - m); sum += p[c2]; }
  float inv = 1.f / sum;
  if (l == 0) {
    #pragma unroll
    for (int c2 = 0; c2 < CC; ++c2) attn[n * CC + c2] = p[c2] * inv;
  }
  float pv = fin * wpL[l];
  #pragma unroll
  for (int o = 32; o > 0; o >>= 1) pv += __shfl_xor(pv, o, 64);
  if (l == 0) pred[n] = pv + bp[0];
}

extern "C" void kernel_launch(void* const* d_in, const int* in_sizes, int n_in,
                              void* d_out, int out_size, void* d_ws, size_t ws_size,
                              hipStream_t stream) {
  (void)in_sizes; (void)n_in; (void)out_size; (void)ws_size;
  const float* nf   = (const float*)d_in[0];
  const int*   edg  = (const int*)d_in[1];
  const float* Wt1  = (const float*)d_in[2];
  const float* bt1  = (const float*)d_in[3];
  const float* Wt2  = (const float*)d_in[4];
  const float* bt2  = (const float*)d_in[5];
  const float* Wci  = (const float*)d_in[6];
  const float* bci  = (const float*)d_in[7];
  const float* Wa1  = (const float*)d_in[8];
  const float* ba1  = (const float*)d_in[9];
  const float* Wa2  = (const float*)d_in[10];
  const float* ba2  = (const float*)d_in[11];
  const float* Wih  = (const float*)d_in[12];
  const float* Whh  = (const float*)d_in[13];
  const float* bih  = (const float*)d_in[14];
  const float* bhh  = (const float*)d_in[15];
  const float* Wag1 = (const float*)d_in[16];
  const float* bag1 = (const float*)d_in[17];
  const float* Wag2 = (const float*)d_in[18];
  const float* bag2 = (const float*)d_in[19];
  const float* Wp   = (const float*)d_in[20];
  const float* bp   = (const float*)d_in[21];

  float* ws   = (float*)d_ws;
  float* ne1  = ws + WS_NE1;
  float* ne   = ws + WS_NE;
  float* s    = ws + WS_S;
  float* np   = ws + WS_NP;
  float* mask = ws + WS_MASK;
  float* ag1  = ws + WS_AG1;
  float* part = ws + WS_PART;

  float* out_stacked = (float*)d_out;                       // [N][C][H]
  float* out_final   = out_stacked + (size_t)NN * CC * HH;  // [N][H]
  float* out_attn    = out_final + (size_t)NN * HH;         // [N][C]
  float* out_pred    = out_attn + (size_t)NN * CC;          // [N]

  // mask (independent)
  zero_mask_k<<<4, 256, 0, stream>>>(mask);
  scatter_mask_k<<<EE / 256, 256, 0, stream>>>(edg, mask);
  // trunk layer 1: split-K=4 over K=256
  gemm_k<0><<<dim3(16, 1, 4), 256, 0, stream>>>(nf, Wt1, nullptr, part, DD, 64, HH, 64, 0, (long)NN * HH);
  reduceZ_k<4, 1><<<64, 256, 0, stream>>>(part, bt1, ne1);
  // trunk layer 2
  gemm_k<1><<<dim3(16, 1, 1), 256, 0, stream>>>(ne1, Wt2, bt2, ne, HH, HH, HH, 0, 0, 0);
  // states0 -> s[c][n][h]
  gemm_k<2><<<dim3(16, CC, 1), 256, 0, stream>>>(ne, Wci, bci, s, HH, HH, CC * HH, 0, 0, 0);
  // nodes_part[c] = ne @ Wa1[c][64:128]
  gemm_k<0><<<dim3(16, 1, CC), 256, 0, stream>>>(ne, Wa1 + HH * HH, nullptr, np, HH, HH, HH, 0,
                                                 (long)2 * HH * HH, (long)NN * HH);
  // 3 sequential fused steps; step 2 also writes out_stacked (fused transpose)
  for (int step = 0; step < 3; ++step)
    fused_step<<<dim3(32, CC), 256, 0, stream>>>(ne, np, mask, Wa1, ba1, Wa2, ba2,
                                                 Wih, Whh, bih, bhh, s,
                                                 step == 2 ? out_stacked : nullptr);
  // aggregate layer 1: split-K=8 over K=1280
  gemm_k<0><<<dim3(16, 1, 8), 256, 0, stream>>>(out_stacked, Wag1, nullptr, part, CC * HH, 160, HH,
                                                160, 0, (long)NN * HH);
  reduceZ_k<8, 1><<<64, 256, 0, stream>>>(part, bag1, ag1);
  // fused: final = ag1 @ Wag2 + bag2; chain-attention softmax; pred
  attn_pred_k<<<NN / 4, 256, 0, stream>>>(ag1, s, Wag2, bag2, Wp, bp,
                                          out_final, out_attn, out_pred);
}